// Round 4
// baseline (532.538 us; speedup 1.0000x reference)
//
#include <hip/hip_runtime.h>

typedef __attribute__((ext_vector_type(8))) short short8v;
typedef __attribute__((ext_vector_type(8))) unsigned short ushort8v;
typedef __attribute__((ext_vector_type(4))) unsigned short ushort4v;
typedef __attribute__((ext_vector_type(4))) float f32x4;

__device__ __forceinline__ unsigned short f2b(float f) {
  unsigned int u = __float_as_uint(f);
  unsigned int r = (u + 0x7FFFu + ((u >> 16) & 1u)) >> 16;
  return (unsigned short)r;
}
__device__ __forceinline__ float b2f(unsigned short h) {
  return __uint_as_float(((unsigned int)h) << 16);
}
__device__ __forceinline__ float gelu_f(float x) {
  float z = 0.7978845608028654f * (x + 0.044715f * x * x * x);
  float e = __expf(2.0f * z);
  float t = 1.0f - 2.0f / (e + 1.0f);   // tanh(z), stable at +/-inf
  return 0.5f * x * (1.0f + t);
}
// async global->LDS, 16B per lane. LDS dest must be wave-uniform base + lane*16.
__device__ __forceinline__ void gload16(const void* g, void* l) {
  __builtin_amdgcn_global_load_lds((const __attribute__((address_space(1))) unsigned int*)g,
                                   (__attribute__((address_space(3))) unsigned int*)l,
                                   16, 0, 0);
}

// ---------------- transpose + f32->bf16 convert: w[K][N] -> wt[N][K] ----------------
__global__ __launch_bounds__(256) void k_transpose_cvt(const float* __restrict__ w,
                                                       unsigned short* __restrict__ wt,
                                                       int K, int N) {
  __shared__ float tile[64][65];
  int tn = blockIdx.x * 64, tk = blockIdx.y * 64;
  int c = threadIdx.x & 63, r0 = threadIdx.x >> 6;
#pragma unroll
  for (int p = 0; p < 16; ++p) {
    int r = r0 + p * 4;
    tile[r][c] = w[(size_t)(tk + r) * N + tn + c];
  }
  __syncthreads();
#pragma unroll
  for (int p = 0; p < 16; ++p) {
    int r = r0 + p * 4;
    wt[(size_t)(tn + r) * K + tk + c] = f2b(tile[c][r]);
  }
}

// ---------------- elementwise f32 -> bf16 ----------------
__global__ void k_cvt_bf16(const float* __restrict__ in, unsigned short* __restrict__ out, int n) {
  int i = blockIdx.x * 256 + threadIdx.x;
  if (i < n) out[i] = f2b(in[i]);
}

// ---------------- LayerNorm over C=1024, out bf16 ----------------
__global__ __launch_bounds__(256) void k_ln(const float* __restrict__ in,
                                            const float* __restrict__ g,
                                            const float* __restrict__ b,
                                            unsigned short* __restrict__ out) {
  int row = blockIdx.x;
  const float* x = in + (size_t)row * 1024;
  int t = threadIdx.x;
  float v0 = x[t], v1 = x[t + 256], v2 = x[t + 512], v3 = x[t + 768];
  float s = v0 + v1 + v2 + v3;
  float s2 = v0 * v0 + v1 * v1 + v2 * v2 + v3 * v3;
#pragma unroll
  for (int m = 1; m < 64; m <<= 1) { s += __shfl_xor(s, m); s2 += __shfl_xor(s2, m); }
  __shared__ float rs[4], rs2[4];
  int w = t >> 6;
  if ((t & 63) == 0) { rs[w] = s; rs2[w] = s2; }
  __syncthreads();
  s = rs[0] + rs[1] + rs[2] + rs[3];
  s2 = rs2[0] + rs2[1] + rs2[2] + rs2[3];
  float mean = s * (1.0f / 1024.0f);
  float var = s2 * (1.0f / 1024.0f) - mean * mean;
  float rinv = rsqrtf(var + 1e-5f);
  unsigned short* o = out + (size_t)row * 1024;
  o[t]       = f2b((v0 - mean) * rinv * g[t]       + b[t]);
  o[t + 256] = f2b((v1 - mean) * rinv * g[t + 256] + b[t + 256]);
  o[t + 512] = f2b((v2 - mean) * rinv * g[t + 512] + b[t + 512]);
  o[t + 768] = f2b((v3 - mean) * rinv * g[t + 768] + b[t + 768]);
}

// ---------------- 256x256 8-phase GEMM (T2+T3+T4+T5), BK=64, 8 waves ----------------
// out[M][N] = A[M][K] @ W[N][K]^T (+bias)(+gelu). M,N multiples of 256; K of 64.
// LDS ring: 8 slots x 16KB: slot = (tile&1)*4 + id, id: 0=A-ks0,1=B-ks0,2=A-ks1,3=B-ks1.
// Each slot = [256 rows][32 k] u16, chunk-swizzled cs^((row>>1)&3) (src-pre-swizzled).
// Phase g of tile T (g=4T+q): stages half g+6; group-top vmcnt(4) (last tile: 0).
template <bool GELU, bool BIAS, bool WF32, bool WBF16>
__global__ __launch_bounds__(512, 2) void k_gemm256(
    const unsigned short* __restrict__ A, int lda,
    const unsigned short* __restrict__ W, int ldw,
    const float* __restrict__ bias,
    float* __restrict__ outF, unsigned short* __restrict__ outB, int ldo,
    int K, size_t zA, size_t zW, size_t zO) {
  __shared__ unsigned short lds[65536];
  int t = threadIdx.x;
  int bz = blockIdx.z;
  A += (size_t)bz * zA;
  W += (size_t)bz * zW;
  if (WF32) outF += (size_t)bz * zO;
  int tileM = blockIdx.y * 256, tileN = blockIdx.x * 256;
  int lane = t & 63, w = t >> 6;
  int wm = w >> 2, wn = w & 3;
  int lr16 = lane & 15, kc4 = lane >> 4;

  // staging sources: thread t owns chunks e=t and e=t+512 of each 16KB half
  int row1 = t >> 2, cs1 = t & 3;
  int row2 = row1 + 128;
  int c1 = (cs1 ^ ((row1 >> 1) & 3)) * 8;
  int c2 = (cs1 ^ ((row2 >> 1) & 3)) * 8;
  const unsigned short* a1 = A + (size_t)(tileM + row1) * lda + c1;
  const unsigned short* a2 = A + (size_t)(tileM + row2) * lda + c2;
  const unsigned short* w1 = W + (size_t)(tileN + row1) * ldw + c1;
  const unsigned short* w2 = W + (size_t)(tileN + row2) * ldw + c2;

  f32x4 acc[8][4];
#pragma unroll
  for (int i = 0; i < 8; ++i)
#pragma unroll
    for (int j = 0; j < 4; ++j) acc[i][j] = f32x4{0.f, 0.f, 0.f, 0.f};

  int ntiles = K >> 6;
  int H = ntiles * 4;

#define STAGE_HALF(h)                                                        \
  do {                                                                       \
    int tile_s = (h) >> 2, id = (h) & 3, slot = (h) & 7;                     \
    int koff = tile_s * 64 + (id >> 1) * 32;                                 \
    unsigned short* dst = &lds[slot * 8192 + t * 8];                         \
    if (id & 1) { gload16(w1 + koff, dst); gload16(w2 + koff, dst + 4096); } \
    else        { gload16(a1 + koff, dst); gload16(a2 + koff, dst + 4096); } \
  } while (0)

  // prologue: halves 0..5 (tile0 complete + tile1 ks0 A,B)
#pragma unroll
  for (int h = 0; h < 6; ++h) STAGE_HALF(h);

  for (int T = 0; T < ntiles; ++T) {
    if (T == ntiles - 1) asm volatile("s_waitcnt vmcnt(0)" ::: "memory");
    else                 asm volatile("s_waitcnt vmcnt(4)" ::: "memory");
    __builtin_amdgcn_s_barrier();
    asm volatile("" ::: "memory");
    int abase = (T & 1) * 4 * 8192;
    short8v bf_[4];
#pragma unroll
    for (int q = 0; q < 4; ++q) {
      const int ks = q >> 1, mh = q & 1;
      int aoff = abase + 2 * ks * 8192;
      int boff = abase + (1 + 2 * ks) * 8192;
      short8v af_[4];
#pragma unroll
      for (int m4 = 0; m4 < 4; ++m4) {
        int row = wm * 128 + (mh * 4 + m4) * 16 + lr16;
        af_[m4] = *(const short8v*)&lds[aoff + row * 32 + (kc4 ^ ((row >> 1) & 3)) * 8];
      }
      if (mh == 0) {
#pragma unroll
        for (int n = 0; n < 4; ++n) {
          int row = wn * 64 + n * 16 + lr16;
          bf_[n] = *(const short8v*)&lds[boff + row * 32 + (kc4 ^ ((row >> 1) & 3)) * 8];
        }
      }
      int h = T * 4 + q + 6;
      if (h < H) STAGE_HALF(h);
      __builtin_amdgcn_s_barrier();
      asm volatile("s_waitcnt lgkmcnt(0)" ::: "memory");
      __builtin_amdgcn_sched_barrier(0);
      __builtin_amdgcn_s_setprio(1);
#pragma unroll
      for (int m4 = 0; m4 < 4; ++m4)
#pragma unroll
        for (int n = 0; n < 4; ++n)
          acc[mh * 4 + m4][n] =
              __builtin_amdgcn_mfma_f32_16x16x32_bf16(af_[m4], bf_[n], acc[mh * 4 + m4][n], 0, 0, 0);
      __builtin_amdgcn_s_setprio(0);
      __builtin_amdgcn_sched_barrier(0);
      __builtin_amdgcn_s_barrier();
      asm volatile("" ::: "memory");
    }
  }
#undef STAGE_HALF

#pragma unroll
  for (int mi = 0; mi < 8; ++mi) {
#pragma unroll
    for (int n = 0; n < 4; ++n) {
      int col = tileN + wn * 64 + n * 16 + lr16;
      float bv = BIAS ? bias[col] : 0.0f;
#pragma unroll
      for (int qi = 0; qi < 4; ++qi) {
        int row = tileM + wm * 128 + mi * 16 + kc4 * 4 + qi;
        float v = acc[mi][n][qi] + bv;
        if (GELU) v = gelu_f(v);
        size_t o = (size_t)row * ldo + col;
        if (WF32) outF[o] = v;
        if (WBF16) outB[o] = f2b(v);
      }
    }
  }
}

// ---------------- split-K reduce: hf/hbf = sum_s part[s] + bias ----------------
__global__ __launch_bounds__(256) void k_red4(const float* __restrict__ p,
                                              const float* __restrict__ bias,
                                              float* __restrict__ hf,
                                              unsigned short* __restrict__ hb) {
  size_t i = ((size_t)blockIdx.x * 256 + threadIdx.x) * 4;
  const size_t S = (size_t)4096 * 1024;
  f32x4 v0 = *(const f32x4*)&p[i];
  f32x4 v1 = *(const f32x4*)&p[i + S];
  f32x4 v2 = *(const f32x4*)&p[i + 2 * S];
  f32x4 v3 = *(const f32x4*)&p[i + 3 * S];
  f32x4 bv = *(const f32x4*)&bias[i & 1023];
  f32x4 v = v0 + v1 + v2 + v3 + bv;
  *(f32x4*)&hf[i] = v;
  ushort4v o;
#pragma unroll
  for (int j = 0; j < 4; ++j) o[j] = f2b(v[j]);
  *(ushort4v*)&hb[i] = o;
}

// ---------------- GEMM 128x128 (2ph counted-vmcnt), kept for small-N ops ----------------
template <bool GELU, bool WF32, bool WBF16, int NRES>
__global__ __launch_bounds__(256) void k_gemm(const unsigned short* __restrict__ A,
                                              const unsigned short* __restrict__ W,
                                              const float* __restrict__ bias,
                                              const float* __restrict__ res1,
                                              const float* __restrict__ res2,
                                              float* __restrict__ outF,
                                              unsigned short* __restrict__ outB,
                                              int M, int N, int K) {
  __shared__ unsigned short sm[2][8192];
  int t = threadIdx.x;
  int tile_n = blockIdx.x * 128, tile_m = blockIdx.y * 128;
  int lane = t & 63, w = t >> 6;
  int wm = (w >> 1) * 64, wn = (w & 1) * 64;
  int lr = lane & 15;
  int kc = lane >> 4;

  int row0 = t >> 2, row1 = 64 + (t >> 2);
  int s0 = t & 3;
  int colA0 = (s0 ^ ((row0 >> 1) & 3)) * 8;
  int colA1 = (s0 ^ ((row1 >> 1) & 3)) * 8;
  int grA0 = tile_m + row0; if (grA0 >= M) grA0 = M - 1;
  int grA1 = tile_m + row1; if (grA1 >= M) grA1 = M - 1;
  const unsigned short* gA0 = A + (size_t)grA0 * K + colA0;
  const unsigned short* gA1 = A + (size_t)grA1 * K + colA1;
  const unsigned short* gB0 = W + (size_t)(tile_n + row0) * K + colA0;
  const unsigned short* gB1 = W + (size_t)(tile_n + row1) * K + colA1;

  f32x4 acc[4][4];
#pragma unroll
  for (int i = 0; i < 4; ++i)
#pragma unroll
    for (int j = 0; j < 4; ++j) acc[i][j] = f32x4{0.f, 0.f, 0.f, 0.f};

  int nsteps = K >> 5;
  gload16(gA0, &sm[0][t * 8]);
  gload16(gA1, &sm[0][2048 + t * 8]);
  gload16(gB0, &sm[0][4096 + t * 8]);
  gload16(gB1, &sm[0][6144 + t * 8]);

  for (int ks = 0; ks < nsteps; ++ks) {
    int cur = ks & 1, nxt = cur ^ 1;
    if (ks + 1 < nsteps) {
      int off = (ks + 1) << 5;
      gload16(gA0 + off, &sm[nxt][t * 8]);
      gload16(gA1 + off, &sm[nxt][2048 + t * 8]);
      gload16(gB0 + off, &sm[nxt][4096 + t * 8]);
      gload16(gB1 + off, &sm[nxt][6144 + t * 8]);
      asm volatile("s_waitcnt vmcnt(4)" ::: "memory");
    } else {
      asm volatile("s_waitcnt vmcnt(0)" ::: "memory");
    }
    __builtin_amdgcn_s_barrier();
    asm volatile("" ::: "memory");
    const unsigned short* buf = &sm[cur][0];
    short8v af[4], bfr[4];
#pragma unroll
    for (int i = 0; i < 4; ++i) {
      int rA = wm + i * 16 + lr;
      int sl = (kc ^ ((rA >> 1) & 3)) * 8;
      af[i] = *(const short8v*)&buf[rA * 32 + sl];
    }
#pragma unroll
    for (int j = 0; j < 4; ++j) {
      int rB = wn + j * 16 + lr;
      int sl = (kc ^ ((rB >> 1) & 3)) * 8;
      bfr[j] = *(const short8v*)&buf[4096 + rB * 32 + sl];
    }
#pragma unroll
    for (int i = 0; i < 4; ++i)
#pragma unroll
      for (int j = 0; j < 4; ++j)
        acc[i][j] = __builtin_amdgcn_mfma_f32_16x16x32_bf16(af[i], bfr[j], acc[i][j], 0, 0, 0);
    asm volatile("" ::: "memory");
    __builtin_amdgcn_s_barrier();
  }

  int r0 = (lane >> 4) * 4;
#pragma unroll
  for (int i = 0; i < 4; ++i) {
#pragma unroll
    for (int j = 0; j < 4; ++j) {
      int col = tile_n + wn + j * 16 + lr;
      float bv = bias[col];
#pragma unroll
      for (int q = 0; q < 4; ++q) {
        int row = tile_m + wm + i * 16 + r0 + q;
        if (row < M) {
          float v = acc[i][j][q] + bv;
          if (GELU) v = gelu_f(v);
          size_t o = (size_t)row * N + col;
          if (NRES >= 1) v += res1[o];
          if (NRES >= 2) v += res2[o];
          if (WF32) outF[o] = v;
          if (WBF16) outB[o] = f2b(v);
        }
      }
    }
  }
}

// ---------------- V transpose: src[b*TB+tok][src_off+h*64+d] -> dst[bh][d][tok] ----------------
__global__ __launch_bounds__(256) void k_vtrans(const unsigned short* __restrict__ src,
                                                int src_stride, int src_off, int TB,
                                                unsigned short* __restrict__ dst, int dst_tstride) {
  __shared__ unsigned short tile[64][72];
  int tb = blockIdx.x, bh = blockIdx.y;
  int b = bh >> 4, h = bh & 15;
  int t = threadIdx.x;
  int r = t >> 2, c0 = (t & 3) * 16;
  int tok = tb * 64 + r; if (tok >= TB) tok = TB - 1;
  const unsigned short* s = src + (size_t)(b * TB + tok) * src_stride + src_off + h * 64 + c0;
  *(ushort8v*)&tile[r][c0] = *(const ushort8v*)s;
  *(ushort8v*)&tile[r][c0 + 8] = *(const ushort8v*)(s + 8);
  __syncthreads();
  unsigned short tmp[16];
#pragma unroll
  for (int j = 0; j < 16; ++j) tmp[j] = tile[c0 + j][r];
  unsigned short* dp = dst + ((size_t)bh * 64 + r) * dst_tstride + tb * 64 + c0;
  *(ushort8v*)dp = *(const ushort8v*)&tmp[0];
  *(ushort8v*)(dp + 8) = *(const ushort8v*)&tmp[8];
}

// ---------------- MFMA flash attention ----------------
template <bool CAUSAL>
__global__ __launch_bounds__(256) void k_attn(
    const unsigned short* __restrict__ Qb, int q_stride,
    const unsigned short* __restrict__ Kb, int k_stride, int k_off, int TKR,
    const unsigned short* __restrict__ Vt, int vt_tstride,
    unsigned short* __restrict__ out, int Tk) {
  __shared__ unsigned short Kl[64 * 72];
  __shared__ unsigned short Vl[64 * 72];
  __shared__ unsigned short Pl[4][16 * 72];
  int qb = blockIdx.x, bh = blockIdx.y;
  int b = bh >> 4, h = bh & 15;
  int t = threadIdx.x, lane = t & 63, w = t >> 6;
  int g = lane >> 4, lc = lane & 15;

  int qrow_g = qb * 64 + w * 16 + lc;
  const unsigned short* qp = Qb + (size_t)(b * 1024 + qrow_g) * q_stride + h * 64 + g * 8;
  short8v aq0 = *(const short8v*)qp;
  short8v aq1 = *(const short8v*)(qp + 32);

  f32x4 o[4];
  float m_[4], l_[4];
#pragma unroll
  for (int dt = 0; dt < 4; ++dt) o[dt] = f32x4{0.f, 0.f, 0.f, 0.f};
#pragma unroll
  for (int r = 0; r < 4; ++r) { m_[r] = -3.0e38f; l_[r] = 0.0f; }

  int srow = t >> 2;
  int sc = (t & 3) * 16;
  int ntiles = CAUSAL ? (qb + 1) : ((Tk + 63) >> 6);

  for (int kt = 0; kt < ntiles; ++kt) {
    __syncthreads();
    {
      int kg = kt * 64 + srow;
      if (!CAUSAL && kg >= Tk) kg = Tk - 1;
      const unsigned short* ks = Kb + (size_t)(b * TKR + kg) * k_stride + k_off + h * 64 + sc;
      *(ushort8v*)&Kl[srow * 72 + sc]     = *(const ushort8v*)ks;
      *(ushort8v*)&Kl[srow * 72 + sc + 8] = *(const ushort8v*)(ks + 8);
      const unsigned short* vs = Vt + ((size_t)bh * 64 + srow) * vt_tstride + kt * 64 + sc;
      *(ushort8v*)&Vl[srow * 72 + sc]     = *(const ushort8v*)vs;
      *(ushort8v*)&Vl[srow * 72 + sc + 8] = *(const ushort8v*)(vs + 8);
    }
    __syncthreads();

    f32x4 s[4];
#pragma unroll
    for (int jt = 0; jt < 4; ++jt) {
      short8v bk0 = *(const short8v*)&Kl[(jt * 16 + lc) * 72 + g * 8];
      short8v bk1 = *(const short8v*)&Kl[(jt * 16 + lc) * 72 + g * 8 + 32];
      f32x4 acc = f32x4{0.f, 0.f, 0.f, 0.f};
      acc = __builtin_amdgcn_mfma_f32_16x16x32_bf16(aq0, bk0, acc, 0, 0, 0);
      acc = __builtin_amdgcn_mfma_f32_16x16x32_bf16(aq1, bk1, acc, 0, 0, 0);
      s[jt] = acc;
    }
#pragma unroll
    for (int jt = 0; jt < 4; ++jt)
#pragma unroll
      for (int r = 0; r < 4; ++r) {
        float sv = s[jt][r] * 0.125f;
        bool masked = CAUSAL ? (kt == qb && (jt * 16 + lc) > (w * 16 + g * 4 + r))
                             : (kt * 64 + jt * 16 + lc >= Tk);
        s[jt][r] = masked ? -3.0e38f : sv;
      }
    float f[4];
#pragma unroll
    for (int r = 0; r < 4; ++r) {
      float mx = fmaxf(fmaxf(s[0][r], s[1][r]), fmaxf(s[2][r], s[3][r]));
      mx = fmaxf(mx, __shfl_xor(mx, 1));
      mx = fmaxf(mx, __shfl_xor(mx, 2));
      mx = fmaxf(mx, __shfl_xor(mx, 4));
      mx = fmaxf(mx, __shfl_xor(mx, 8));
      float mnew = fmaxf(m_[r], mx);
      f[r] = __expf(m_[r] - mnew);
      m_[r] = mnew;
      float rsum = 0.0f;
#pragma unroll
      for (int jt = 0; jt < 4; ++jt) {
        float p = __expf(s[jt][r] - mnew);
        s[jt][r] = p;
        rsum += p;
      }
      rsum += __shfl_xor(rsum, 1);
      rsum += __shfl_xor(rsum, 2);
      rsum += __shfl_xor(rsum, 4);
      rsum += __shfl_xor(rsum, 8);
      l_[r] = l_[r] * f[r] + rsum;
    }
#pragma unroll
    for (int dt = 0; dt < 4; ++dt)
#pragma unroll
      for (int r = 0; r < 4; ++r) o[dt][r] *= f[r];
#pragma unroll
    for (int jt = 0; jt < 4; ++jt)
#pragma unroll
      for (int r = 0; r < 4; ++r)
        Pl[w][(g * 4 + r) * 72 + jt * 16 + lc] = f2b(s[jt][r]);
    short8v ap0 = *(const short8v*)&Pl[w][lc * 72 + g * 8];
    short8v ap1 = *(const short8v*)&Pl[w][lc * 72 + g * 8 + 32];
#pragma unroll
    for (int dt = 0; dt < 4; ++dt) {
      short8v bv0 = *(const short8v*)&Vl[(dt * 16 + lc) * 72 + g * 8];
      short8v bv1 = *(const short8v*)&Vl[(dt * 16 + lc) * 72 + g * 8 + 32];
      o[dt] = __builtin_amdgcn_mfma_f32_16x16x32_bf16(ap0, bv0, o[dt], 0, 0, 0);
      o[dt] = __builtin_amdgcn_mfma_f32_16x16x32_bf16(ap1, bv1, o[dt], 0, 0, 0);
    }
  }
  size_t orow = (size_t)(b * 1024 + qb * 64 + w * 16) * 1024 + h * 64;
#pragma unroll
  for (int r = 0; r < 4; ++r) {
    float inv = 1.0f / l_[r];
#pragma unroll
    for (int dt = 0; dt < 4; ++dt)
      out[orow + (size_t)(g * 4 + r) * 1024 + dt * 16 + lc] = f2b(o[dt][r] * inv);
  }
}

extern "C" void kernel_launch(void* const* d_in, const int* in_sizes, int n_in,
                              void* d_out, int out_size, void* d_ws, size_t ws_size,
                              hipStream_t stream) {
  (void)in_sizes; (void)n_in; (void)out_size;
  const float* x       = (const float*)d_in[0];
  const float* enc     = (const float*)d_in[1];
  const float* ln1_g   = (const float*)d_in[3];
  const float* ln1_b   = (const float*)d_in[4];
  const float* ln2_g   = (const float*)d_in[5];
  const float* ln2_b   = (const float*)d_in[6];
  const float* ln3_g   = (const float*)d_in[7];
  const float* ln3_b   = (const float*)d_in[8];
  const float* attn_w  = (const float*)d_in[9];
  const float* attn_b  = (const float*)d_in[10];
  const float* aproj_w = (const float*)d_in[11];
  const float* aproj_b = (const float*)d_in[12];
  const float* ca_w    = (const float*)d_in[13];
  const float* ca_b    = (const float*)d_in[14];
  const float* caproj_w= (const float*)d_in[15];
  const float* caproj_b= (const float*)d_in[16];
  const float* fc_w    = (const float*)d_in[17];
  const float* fc_b    = (const float*)d_in[18];
  const float* mproj_w = (const float*)d_in[19];
  const float* mproj_b = (const float*)d_in[20];
  const float* down_w  = (const float*)d_in[21];
  const float* down_b  = (const float*)d_in[22];
  const float* up_w    = (const float*)d_in[23];
  const float* up_b    = (const float*)d_in[24];
  float* out = (float*)d_out;
  char* ws = (char*)d_ws;

  const size_t O_WATTN = 0, O_WAPROJ = 6291456, O_WCA = 8388608, O_WCAPROJ = 14680064,
               O_WFC = 16777216, O_WMPROJ = 25165824, O_WDOWN = 33554432, O_WUP = 34078720,
               O_ENC = 34603008, O_LN = 36708352, O_BIG = 45096960,
               O_XRES = 78651392, O_HF = 95428608, O_ATTN = 112205824,
               O_PART = 121634816;

  unsigned short* wt_attn   = (unsigned short*)(ws + O_WATTN);
  unsigned short* wt_aproj  = (unsigned short*)(ws + O_WAPROJ);
  unsigned short* wt_ca     = (unsigned short*)(ws + O_WCA);
  unsigned short* wt_caproj = (unsigned short*)(ws + O_WCAPROJ);
  unsigned short* wt_fc     = (unsigned short*)(ws + O_WFC);
  unsigned short* wt_mproj  = (unsigned short*)(ws + O_WMPROJ);
  unsigned short* wt_down   = (unsigned short*)(ws + O_WDOWN);
  unsigned short* wt_up     = (unsigned short*)(ws + O_WUP);
  unsigned short* encbf     = (unsigned short*)(ws + O_ENC);
  unsigned short* lnout     = (unsigned short*)(ws + O_LN);
  unsigned short* hbf       = (unsigned short*)(ws + O_LN);            // after fc consumed
  unsigned short* qkvb      = (unsigned short*)(ws + O_BIG);
  unsigned short* vt_self   = (unsigned short*)(ws + O_BIG + 25165824); // alive with qkvb
  unsigned short* q2b       = (unsigned short*)(ws + O_BIG);           // after self path done
  unsigned short* kvb       = (unsigned short*)(ws + O_BIG + 8388608);
  unsigned short* vt_cross  = (unsigned short*)(ws + O_BIG + 12599296);
  unsigned short* caout     = (unsigned short*)(ws + O_BIG + 15220736);
  unsigned short* fcout     = (unsigned short*)(ws + O_BIG);           // after cross path done
  float*          xres      = (float*)(ws + O_XRES);
  float*          hf        = (float*)(ws + O_HF);
  unsigned short* attnout   = (unsigned short*)(ws + O_ATTN);
  unsigned short* dmid      = (unsigned short*)(ws + O_ATTN);          // after aproj consumed
  float*          part      = (float*)(ws + O_PART);

  bool splitk = ws_size >= O_PART + 4ull * 4096 * 1024 * 4;

  dim3 blk(256);
  dim3 blk5(512);

  // 1. weight transposes (f32 [K][N] -> bf16 [N][K])
  k_transpose_cvt<<<dim3(48, 16), blk, 0, stream>>>(attn_w,  wt_attn,   1024, 3072);
  k_transpose_cvt<<<dim3(16, 16), blk, 0, stream>>>(aproj_w, wt_aproj,  1024, 1024);
  k_transpose_cvt<<<dim3(48, 16), blk, 0, stream>>>(ca_w,    wt_ca,     1024, 3072);
  k_transpose_cvt<<<dim3(16, 16), blk, 0, stream>>>(caproj_w,wt_caproj, 1024, 1024);
  k_transpose_cvt<<<dim3(64, 16), blk, 0, stream>>>(fc_w,    wt_fc,     1024, 4096);
  k_transpose_cvt<<<dim3(16, 64), blk, 0, stream>>>(mproj_w, wt_mproj,  4096, 1024);
  k_transpose_cvt<<<dim3(4, 16),  blk, 0, stream>>>(down_w,  wt_down,   1024, 256);
  k_transpose_cvt<<<dim3(16, 4),  blk, 0, stream>>>(up_w,    wt_up,     256,  1024);
  // 2. encoder -> bf16
  k_cvt_bf16<<<dim3(4112), blk, 0, stream>>>(enc, encbf, 1028 * 1024);

  // 3. ln1(x) ; qkv(8ph 256²) ; V-transpose ; self-attn ; aproj + residual(x) -> xres
  k_ln<<<dim3(4096), blk, 0, stream>>>(x, ln1_g, ln1_b, lnout);
  k_gemm256<false, true, false, true><<<dim3(12, 16), blk5, 0, stream>>>(
      lnout, 1024, wt_attn, 1024, attn_b, nullptr, qkvb, 3072, 1024, 0, 0, 0);
  k_vtrans<<<dim3(16, 64), blk, 0, stream>>>(qkvb, 3072, 2048, 1024, vt_self, 1024);
  k_attn<true><<<dim3(16, 64), blk, 0, stream>>>(
      qkvb, 3072, qkvb, 3072, 1024, 1024, vt_self, 1024, attnout, 1024);
  k_gemm<false, true, false, 1><<<dim3(8, 32), blk, 0, stream>>>(
      attnout, wt_aproj, aproj_b, x, nullptr, xres, nullptr, 4096, 1024, 1024);

  // 4. ln2(xres) ; q2 ; kv(enc) ; V-transpose ; cross-attn ; caproj + residual -> xres
  k_ln<<<dim3(4096), blk, 0, stream>>>(xres, ln2_g, ln2_b, lnout);
  k_gemm<false, false, true, 0><<<dim3(8, 32), blk, 0, stream>>>(
      lnout, wt_ca, ca_b, nullptr, nullptr, nullptr, q2b, 4096, 1024, 1024);
  k_gemm<false, false, true, 0><<<dim3(16, 9), blk, 0, stream>>>(
      encbf, wt_ca + (size_t)1024 * 1024, ca_b + 1024, nullptr, nullptr, nullptr, kvb,
      1028, 2048, 1024);
  k_vtrans<<<dim3(5, 64), blk, 0, stream>>>(kvb, 2048, 1024, 257, vt_cross, 320);
  k_attn<false><<<dim3(16, 64), blk, 0, stream>>>(
      q2b, 1024, kvb, 2048, 0, 257, vt_cross, 320, caout, 257);
  k_gemm<false, true, false, 1><<<dim3(8, 32), blk, 0, stream>>>(
      caout, wt_caproj, caproj_b, xres, nullptr, xres, nullptr, 4096, 1024, 1024);

  // 5. ln3(xres) ; fc+gelu (8ph 256²) ; mproj (split-K 8ph or 128² fallback)
  k_ln<<<dim3(4096), blk, 0, stream>>>(xres, ln3_g, ln3_b, lnout);
  k_gemm256<true, true, false, true><<<dim3(16, 16), blk5, 0, stream>>>(
      lnout, 1024, wt_fc, 1024, fc_b, nullptr, fcout, 4096, 1024, 0, 0, 0);
  if (splitk) {
    k_gemm256<false, false, true, false><<<dim3(4, 16, 4), blk5, 0, stream>>>(
        fcout, 4096, wt_mproj, 4096, nullptr, part, nullptr, 1024, 1024,
        1024, 1024, (size_t)4096 * 1024);
    k_red4<<<dim3(4096), blk, 0, stream>>>(part, mproj_b, hf, hbf);
  } else {
    k_gemm<false, true, true, 0><<<dim3(8, 32), blk, 0, stream>>>(
        fcout, wt_mproj, mproj_b, nullptr, nullptr, hf, hbf, 4096, 1024, 4096);
  }

  // 6. adapter: down+gelu ; up + up_b + h + xres -> out
  k_gemm<true, false, true, 0><<<dim3(2, 32), blk, 0, stream>>>(
      hbf, wt_down, down_b, nullptr, nullptr, nullptr, dmid, 4096, 256, 1024);
  k_gemm<false, true, false, 2><<<dim3(8, 32), blk, 0, stream>>>(
      dmid, wt_up, up_b, hf, xres, out, nullptr, 4096, 1024, 256);
}

// Round 5
// 504.912 us; speedup vs baseline: 1.0547x; 1.0547x over previous
//
#include <hip/hip_runtime.h>

typedef __attribute__((ext_vector_type(8))) short short8v;
typedef __attribute__((ext_vector_type(8))) unsigned short ushort8v;
typedef __attribute__((ext_vector_type(4))) float f32x4;

__device__ __forceinline__ unsigned short f2b(float f) {
  unsigned int u = __float_as_uint(f);
  unsigned int r = (u + 0x7FFFu + ((u >> 16) & 1u)) >> 16;
  return (unsigned short)r;
}
__device__ __forceinline__ float b2f(unsigned short h) {
  return __uint_as_float(((unsigned int)h) << 16);
}
__device__ __forceinline__ float gelu_f(float x) {
  float z = 0.7978845608028654f * (x + 0.044715f * x * x * x);
  float e = __expf(2.0f * z);
  float t = 1.0f - 2.0f / (e + 1.0f);   // tanh(z), stable at +/-inf
  return 0.5f * x * (1.0f + t);
}
// async global->LDS, 16B per lane. LDS dest must be wave-uniform base + lane*16.
__device__ __forceinline__ void gload16(const void* g, void* l) {
  __builtin_amdgcn_global_load_lds((const __attribute__((address_space(1))) unsigned int*)g,
                                   (__attribute__((address_space(3))) unsigned int*)l,
                                   16, 0, 0);
}

// ---------------- transpose + f32->bf16 convert: w[K][N] -> wt[N][K] ----------------
__global__ __launch_bounds__(256) void k_transpose_cvt(const float* __restrict__ w,
                                                       unsigned short* __restrict__ wt,
                                                       int K, int N) {
  __shared__ float tile[64][65];
  int tn = blockIdx.x * 64, tk = blockIdx.y * 64;
  int c = threadIdx.x & 63, r0 = threadIdx.x >> 6;
#pragma unroll
  for (int p = 0; p < 16; ++p) {
    int r = r0 + p * 4;
    tile[r][c] = w[(size_t)(tk + r) * N + tn + c];
  }
  __syncthreads();
#pragma unroll
  for (int p = 0; p < 16; ++p) {
    int r = r0 + p * 4;
    wt[(size_t)(tn + r) * K + tk + c] = f2b(tile[c][r]);
  }
}

// ---------------- elementwise f32 -> bf16 ----------------
__global__ void k_cvt_bf16(const float* __restrict__ in, unsigned short* __restrict__ out, int n) {
  int i = blockIdx.x * 256 + threadIdx.x;
  if (i < n) out[i] = f2b(in[i]);
}

// ---------------- LayerNorm over C=1024, out bf16 ----------------
__global__ __launch_bounds__(256) void k_ln(const float* __restrict__ in,
                                            const float* __restrict__ g,
                                            const float* __restrict__ b,
                                            unsigned short* __restrict__ out) {
  int row = blockIdx.x;
  const float* x = in + (size_t)row * 1024;
  int t = threadIdx.x;
  float v0 = x[t], v1 = x[t + 256], v2 = x[t + 512], v3 = x[t + 768];
  float s = v0 + v1 + v2 + v3;
  float s2 = v0 * v0 + v1 * v1 + v2 * v2 + v3 * v3;
#pragma unroll
  for (int m = 1; m < 64; m <<= 1) { s += __shfl_xor(s, m); s2 += __shfl_xor(s2, m); }
  __shared__ float rs[4], rs2[4];
  int w = t >> 6;
  if ((t & 63) == 0) { rs[w] = s; rs2[w] = s2; }
  __syncthreads();
  s = rs[0] + rs[1] + rs[2] + rs[3];
  s2 = rs2[0] + rs2[1] + rs2[2] + rs2[3];
  float mean = s * (1.0f / 1024.0f);
  float var = s2 * (1.0f / 1024.0f) - mean * mean;
  float rinv = rsqrtf(var + 1e-5f);
  unsigned short* o = out + (size_t)row * 1024;
  o[t]       = f2b((v0 - mean) * rinv * g[t]       + b[t]);
  o[t + 256] = f2b((v1 - mean) * rinv * g[t + 256] + b[t + 256]);
  o[t + 512] = f2b((v2 - mean) * rinv * g[t + 512] + b[t + 512]);
  o[t + 768] = f2b((v3 - mean) * rinv * g[t + 768] + b[t + 768]);
}

// ---------------- 256x256 single-barrier 2-phase GEMM (T3-minimum recipe) ----------------
// out[M][N] = A[M][K] @ W[N][K]^T + bias (+gelu), bf16 out. M,N mult of 256, K of 64.
// Loop: STAGE(next) ; ds_read cur ; MFMA ; vmcnt(0) ; barrier.  One barrier per K-step.
// LDS 128KB: buf b at u16 b*32768; slabs A0/A1/B0/B1 of [256 rows][32 k] each, 16KB.
// chunk-swizzle: row r slot s holds global chunk s^((r>>1)&3) (src-preswizzled, 0 conflicts).
template <bool GELU>
__global__ __launch_bounds__(512, 2) void k_g256(
    const unsigned short* __restrict__ A, int lda,
    const unsigned short* __restrict__ W, int ldw,
    const float* __restrict__ bias,
    unsigned short* __restrict__ outB, int ldo, int K) {
  __shared__ unsigned short lds[65536];
  const int t = threadIdx.x;
  const int tileM = blockIdx.y * 256, tileN = blockIdx.x * 256;
  const int lane = t & 63, w = t >> 6;
  const int wm = w >> 2, wn = w & 3;
  const int lr16 = lane & 15, kc4 = lane >> 4;

  const int row1 = t >> 2, row2 = row1 + 128, cs = t & 3;
  const int c1 = (cs ^ ((row1 >> 1) & 3)) * 8;
  const int c2 = (cs ^ ((row2 >> 1) & 3)) * 8;
  const unsigned short* a1 = A + (size_t)(tileM + row1) * lda + c1;
  const unsigned short* a2 = A + (size_t)(tileM + row2) * lda + c2;
  const unsigned short* w1 = W + (size_t)(tileN + row1) * ldw + c1;
  const unsigned short* w2 = W + (size_t)(tileN + row2) * ldw + c2;

  f32x4 acc[8][4];
#pragma unroll
  for (int i = 0; i < 8; ++i)
#pragma unroll
    for (int j = 0; j < 4; ++j) acc[i][j] = f32x4{0.f, 0.f, 0.f, 0.f};

  const int nt = K >> 6;

#define STAGE256(b, koff)                                  \
  do {                                                     \
    unsigned short* dst = &lds[(b) * 32768 + t * 8];       \
    gload16(a1 + (koff), dst);                             \
    gload16(a2 + (koff), dst + 4096);                      \
    gload16(a1 + (koff) + 32, dst + 8192);                 \
    gload16(a2 + (koff) + 32, dst + 12288);                \
    gload16(w1 + (koff), dst + 16384);                     \
    gload16(w2 + (koff), dst + 20480);                     \
    gload16(w1 + (koff) + 32, dst + 24576);                \
    gload16(w2 + (koff) + 32, dst + 28672);                \
  } while (0)

  STAGE256(0, 0);
  asm volatile("s_waitcnt vmcnt(0)" ::: "memory");
  __builtin_amdgcn_s_barrier();

  for (int T = 0; T < nt; ++T) {
    if (T + 1 < nt) STAGE256((T + 1) & 1, (T + 1) * 64);
    const unsigned short* buf = &lds[(T & 1) * 32768];
#pragma unroll
    for (int s = 0; s < 2; ++s) {
      const unsigned short* ab = buf + s * 8192;
      const unsigned short* bb = buf + 16384 + s * 8192;
      short8v bfr[4];
#pragma unroll
      for (int n = 0; n < 4; ++n) {
        int r = wn * 64 + n * 16 + lr16;
        bfr[n] = *(const short8v*)&bb[r * 32 + (kc4 ^ ((r >> 1) & 3)) * 8];
      }
#pragma unroll
      for (int mi = 0; mi < 8; ++mi) {
        int r = wm * 128 + mi * 16 + lr16;
        short8v af = *(const short8v*)&ab[r * 32 + (kc4 ^ ((r >> 1) & 3)) * 8];
#pragma unroll
        for (int n = 0; n < 4; ++n)
          acc[mi][n] = __builtin_amdgcn_mfma_f32_16x16x32_bf16(af, bfr[n], acc[mi][n], 0, 0, 0);
      }
    }
    if (T + 1 < nt) {
      asm volatile("s_waitcnt vmcnt(0)" ::: "memory");
      __builtin_amdgcn_s_barrier();
    }
  }
#undef STAGE256

#pragma unroll
  for (int mi = 0; mi < 8; ++mi) {
#pragma unroll
    for (int n = 0; n < 4; ++n) {
      int col = tileN + wn * 64 + n * 16 + lr16;
      float bv = bias[col];
#pragma unroll
      for (int qi = 0; qi < 4; ++qi) {
        int row = tileM + wm * 128 + mi * 16 + kc4 * 4 + qi;
        float v = acc[mi][n][qi] + bv;
        if (GELU) v = gelu_f(v);
        outB[(size_t)row * ldo + col] = f2b(v);
      }
    }
  }
}

// ---------------- 128x128 single-barrier 2-phase GEMM (M-guarded, residual/epilogue) ----
// LDS 64KB: buf b at u16 b*16384; slabs A0/A1/B0/B1 of [128 rows][32 k], 8KB each.
template <bool GELU, bool WF32, bool WBF16, int NRES>
__global__ __launch_bounds__(256) void k_g128(
    const unsigned short* __restrict__ A, int lda,
    const unsigned short* __restrict__ W, int ldw,
    const float* __restrict__ bias,
    const float* __restrict__ res1, const float* __restrict__ res2,
    float* __restrict__ outF, unsigned short* __restrict__ outB,
    int M, int N, int K) {
  __shared__ unsigned short lds[32768];
  const int t = threadIdx.x;
  const int tileM = blockIdx.y * 128, tileN = blockIdx.x * 128;
  const int lane = t & 63, w = t >> 6;
  const int wm = (w >> 1) * 64, wn = (w & 1) * 64;
  const int lr16 = lane & 15, kc4 = lane >> 4;

  const int row1 = t >> 2, row2 = row1 + 64, cs = t & 3;
  const int c1 = (cs ^ ((row1 >> 1) & 3)) * 8;
  const int c2 = (cs ^ ((row2 >> 1) & 3)) * 8;
  int gr1 = tileM + row1; if (gr1 >= M) gr1 = M - 1;
  int gr2 = tileM + row2; if (gr2 >= M) gr2 = M - 1;
  const unsigned short* a1 = A + (size_t)gr1 * lda + c1;
  const unsigned short* a2 = A + (size_t)gr2 * lda + c2;
  const unsigned short* w1 = W + (size_t)(tileN + row1) * ldw + c1;
  const unsigned short* w2 = W + (size_t)(tileN + row2) * ldw + c2;

  f32x4 acc[4][4];
#pragma unroll
  for (int i = 0; i < 4; ++i)
#pragma unroll
    for (int j = 0; j < 4; ++j) acc[i][j] = f32x4{0.f, 0.f, 0.f, 0.f};

  const int nt = K >> 6;

#define STAGE128(b, koff)                                  \
  do {                                                     \
    unsigned short* dst = &lds[(b) * 16384 + t * 8];       \
    gload16(a1 + (koff), dst);                             \
    gload16(a2 + (koff), dst + 2048);                      \
    gload16(a1 + (koff) + 32, dst + 4096);                 \
    gload16(a2 + (koff) + 32, dst + 6144);                 \
    gload16(w1 + (koff), dst + 8192);                      \
    gload16(w2 + (koff), dst + 10240);                     \
    gload16(w1 + (koff) + 32, dst + 12288);                \
    gload16(w2 + (koff) + 32, dst + 14336);                \
  } while (0)

  STAGE128(0, 0);
  asm volatile("s_waitcnt vmcnt(0)" ::: "memory");
  __builtin_amdgcn_s_barrier();

  for (int T = 0; T < nt; ++T) {
    if (T + 1 < nt) STAGE128((T + 1) & 1, (T + 1) * 64);
    const unsigned short* buf = &lds[(T & 1) * 16384];
#pragma unroll
    for (int s = 0; s < 2; ++s) {
      const unsigned short* ab = buf + s * 4096;
      const unsigned short* bb = buf + 8192 + s * 4096;
      short8v bfr[4];
#pragma unroll
      for (int n = 0; n < 4; ++n) {
        int r = wn + n * 16 + lr16;
        bfr[n] = *(const short8v*)&bb[r * 32 + (kc4 ^ ((r >> 1) & 3)) * 8];
      }
#pragma unroll
      for (int mi = 0; mi < 4; ++mi) {
        int r = wm + mi * 16 + lr16;
        short8v af = *(const short8v*)&ab[r * 32 + (kc4 ^ ((r >> 1) & 3)) * 8];
#pragma unroll
        for (int n = 0; n < 4; ++n)
          acc[mi][n] = __builtin_amdgcn_mfma_f32_16x16x32_bf16(af, bfr[n], acc[mi][n], 0, 0, 0);
      }
    }
    if (T + 1 < nt) {
      asm volatile("s_waitcnt vmcnt(0)" ::: "memory");
      __builtin_amdgcn_s_barrier();
    }
  }
#undef STAGE128

#pragma unroll
  for (int mi = 0; mi < 4; ++mi) {
#pragma unroll
    for (int n = 0; n < 4; ++n) {
      int col = tileN + wn + n * 16 + lr16;
      float bv = bias[col];
#pragma unroll
      for (int qi = 0; qi < 4; ++qi) {
        int row = tileM + wm + mi * 16 + kc4 * 4 + qi;
        if (row < M) {
          float v = acc[mi][n][qi] + bv;
          if (GELU) v = gelu_f(v);
          size_t o = (size_t)row * N + col;
          if (NRES >= 1) v += res1[o];
          if (NRES >= 2) v += res2[o];
          if (WF32) outF[o] = v;
          if (WBF16) outB[o] = f2b(v);
        }
      }
    }
  }
}

// ---------------- V transpose: src[b*TB+tok][src_off+h*64+d] -> dst[bh][d][tok] ----------------
__global__ __launch_bounds__(256) void k_vtrans(const unsigned short* __restrict__ src,
                                                int src_stride, int src_off, int TB,
                                                unsigned short* __restrict__ dst, int dst_tstride) {
  __shared__ unsigned short tile[64][72];
  int tb = blockIdx.x, bh = blockIdx.y;
  int b = bh >> 4, h = bh & 15;
  int t = threadIdx.x;
  int r = t >> 2, c0 = (t & 3) * 16;
  int tok = tb * 64 + r; if (tok >= TB) tok = TB - 1;
  const unsigned short* s = src + (size_t)(b * TB + tok) * src_stride + src_off + h * 64 + c0;
  *(ushort8v*)&tile[r][c0] = *(const ushort8v*)s;
  *(ushort8v*)&tile[r][c0 + 8] = *(const ushort8v*)(s + 8);
  __syncthreads();
  unsigned short tmp[16];
#pragma unroll
  for (int j = 0; j < 16; ++j) tmp[j] = tile[c0 + j][r];
  unsigned short* dp = dst + ((size_t)bh * 64 + r) * dst_tstride + tb * 64 + c0;
  *(ushort8v*)dp = *(const ushort8v*)&tmp[0];
  *(ushort8v*)(dp + 8) = *(const ushort8v*)&tmp[8];
}

// ---------------- MFMA flash attention ----------------
template <bool CAUSAL>
__global__ __launch_bounds__(256) void k_attn(
    const unsigned short* __restrict__ Qb, int q_stride,
    const unsigned short* __restrict__ Kb, int k_stride, int k_off, int TKR,
    const unsigned short* __restrict__ Vt, int vt_tstride,
    unsigned short* __restrict__ out, int Tk) {
  __shared__ unsigned short Kl[64 * 72];
  __shared__ unsigned short Vl[64 * 72];
  __shared__ unsigned short Pl[4][16 * 72];
  int qb = blockIdx.x, bh = blockIdx.y;
  int b = bh >> 4, h = bh & 15;
  int t = threadIdx.x, lane = t & 63, w = t >> 6;
  int g = lane >> 4, lc = lane & 15;

  int qrow_g = qb * 64 + w * 16 + lc;
  const unsigned short* qp = Qb + (size_t)(b * 1024 + qrow_g) * q_stride + h * 64 + g * 8;
  short8v aq0 = *(const short8v*)qp;
  short8v aq1 = *(const short8v*)(qp + 32);

  f32x4 o[4];
  float m_[4], l_[4];
#pragma unroll
  for (int dt = 0; dt < 4; ++dt) o[dt] = f32x4{0.f, 0.f, 0.f, 0.f};
#pragma unroll
  for (int r = 0; r < 4; ++r) { m_[r] = -3.0e38f; l_[r] = 0.0f; }

  int srow = t >> 2;
  int sc = (t & 3) * 16;
  int ntiles = CAUSAL ? (qb + 1) : ((Tk + 63) >> 6);

  for (int kt = 0; kt < ntiles; ++kt) {
    __syncthreads();
    {
      int kg = kt * 64 + srow;
      if (!CAUSAL && kg >= Tk) kg = Tk - 1;
      const unsigned short* ks = Kb + (size_t)(b * TKR + kg) * k_stride + k_off + h * 64 + sc;
      *(ushort8v*)&Kl[srow * 72 + sc]     = *(const ushort8v*)ks;
      *(ushort8v*)&Kl[srow * 72 + sc + 8] = *(const ushort8v*)(ks + 8);
      const unsigned short* vs = Vt + ((size_t)bh * 64 + srow) * vt_tstride + kt * 64 + sc;
      *(ushort8v*)&Vl[srow * 72 + sc]     = *(const ushort8v*)vs;
      *(ushort8v*)&Vl[srow * 72 + sc + 8] = *(const ushort8v*)(vs + 8);
    }
    __syncthreads();

    f32x4 s[4];
#pragma unroll
    for (int jt = 0; jt < 4; ++jt) {
      short8v bk0 = *(const short8v*)&Kl[(jt * 16 + lc) * 72 + g * 8];
      short8v bk1 = *(const short8v*)&Kl[(jt * 16 + lc) * 72 + g * 8 + 32];
      f32x4 acc = f32x4{0.f, 0.f, 0.f, 0.f};
      acc = __builtin_amdgcn_mfma_f32_16x16x32_bf16(aq0, bk0, acc, 0, 0, 0);
      acc = __builtin_amdgcn_mfma_f32_16x16x32_bf16(aq1, bk1, acc, 0, 0, 0);
      s[jt] = acc;
    }
#pragma unroll
    for (int jt = 0; jt < 4; ++jt)
#pragma unroll
      for (int r = 0; r < 4; ++r) {
        float sv = s[jt][r] * 0.125f;
        bool masked = CAUSAL ? (kt == qb && (jt * 16 + lc) > (w * 16 + g * 4 + r))
                             : (kt * 64 + jt * 16 + lc >= Tk);
        s[jt][r] = masked ? -3.0e38f : sv;
      }
    float f[4];
#pragma unroll
    for (int r = 0; r < 4; ++r) {
      float mx = fmaxf(fmaxf(s[0][r], s[1][r]), fmaxf(s[2][r], s[3][r]));
      mx = fmaxf(mx, __shfl_xor(mx, 1));
      mx = fmaxf(mx, __shfl_xor(mx, 2));
      mx = fmaxf(mx, __shfl_xor(mx, 4));
      mx = fmaxf(mx, __shfl_xor(mx, 8));
      float mnew = fmaxf(m_[r], mx);
      f[r] = __expf(m_[r] - mnew);
      m_[r] = mnew;
      float rsum = 0.0f;
#pragma unroll
      for (int jt = 0; jt < 4; ++jt) {
        float p = __expf(s[jt][r] - mnew);
        s[jt][r] = p;
        rsum += p;
      }
      rsum += __shfl_xor(rsum, 1);
      rsum += __shfl_xor(rsum, 2);
      rsum += __shfl_xor(rsum, 4);
      rsum += __shfl_xor(rsum, 8);
      l_[r] = l_[r] * f[r] + rsum;
    }
#pragma unroll
    for (int dt = 0; dt < 4; ++dt)
#pragma unroll
      for (int r = 0; r < 4; ++r) o[dt][r] *= f[r];
#pragma unroll
    for (int jt = 0; jt < 4; ++jt)
#pragma unroll
      for (int r = 0; r < 4; ++r)
        Pl[w][(g * 4 + r) * 72 + jt * 16 + lc] = f2b(s[jt][r]);
    short8v ap0 = *(const short8v*)&Pl[w][lc * 72 + g * 8];
    short8v ap1 = *(const short8v*)&Pl[w][lc * 72 + g * 8 + 32];
#pragma unroll
    for (int dt = 0; dt < 4; ++dt) {
      short8v bv0 = *(const short8v*)&Vl[(dt * 16 + lc) * 72 + g * 8];
      short8v bv1 = *(const short8v*)&Vl[(dt * 16 + lc) * 72 + g * 8 + 32];
      o[dt] = __builtin_amdgcn_mfma_f32_16x16x32_bf16(ap0, bv0, o[dt], 0, 0, 0);
      o[dt] = __builtin_amdgcn_mfma_f32_16x16x32_bf16(ap1, bv1, o[dt], 0, 0, 0);
    }
  }
  size_t orow = (size_t)(b * 1024 + qb * 64 + w * 16) * 1024 + h * 64;
#pragma unroll
  for (int r = 0; r < 4; ++r) {
    float inv = 1.0f / l_[r];
#pragma unroll
    for (int dt = 0; dt < 4; ++dt)
      out[orow + (size_t)(g * 4 + r) * 1024 + dt * 16 + lc] = f2b(o[dt][r] * inv);
  }
}

extern "C" void kernel_launch(void* const* d_in, const int* in_sizes, int n_in,
                              void* d_out, int out_size, void* d_ws, size_t ws_size,
                              hipStream_t stream) {
  (void)in_sizes; (void)n_in; (void)out_size; (void)ws_size;
  const float* x       = (const float*)d_in[0];
  const float* enc     = (const float*)d_in[1];
  const float* ln1_g   = (const float*)d_in[3];
  const float* ln1_b   = (const float*)d_in[4];
  const float* ln2_g   = (const float*)d_in[5];
  const float* ln2_b   = (const float*)d_in[6];
  const float* ln3_g   = (const float*)d_in[7];
  const float* ln3_b   = (const float*)d_in[8];
  const float* attn_w  = (const float*)d_in[9];
  const float* attn_b  = (const float*)d_in[10];
  const float* aproj_w = (const float*)d_in[11];
  const float* aproj_b = (const float*)d_in[12];
  const float* ca_w    = (const float*)d_in[13];
  const float* ca_b    = (const float*)d_in[14];
  const float* caproj_w= (const float*)d_in[15];
  const float* caproj_b= (const float*)d_in[16];
  const float* fc_w    = (const float*)d_in[17];
  const float* fc_b    = (const float*)d_in[18];
  const float* mproj_w = (const float*)d_in[19];
  const float* mproj_b = (const float*)d_in[20];
  const float* down_w  = (const float*)d_in[21];
  const float* down_b  = (const float*)d_in[22];
  const float* up_w    = (const float*)d_in[23];
  const float* up_b    = (const float*)d_in[24];
  float* out = (float*)d_out;
  char* ws = (char*)d_ws;

  const size_t O_WATTN = 0, O_WAPROJ = 6291456, O_WCA = 8388608, O_WCAPROJ = 14680064,
               O_WFC = 16777216, O_WMPROJ = 25165824, O_WDOWN = 33554432, O_WUP = 34078720,
               O_ENC = 34603008, O_LN = 36708352, O_BIG = 45096960,
               O_XRES = 78651392, O_HF = 95428608, O_ATTN = 112205824;

  unsigned short* wt_attn   = (unsigned short*)(ws + O_WATTN);
  unsigned short* wt_aproj  = (unsigned short*)(ws + O_WAPROJ);
  unsigned short* wt_ca     = (unsigned short*)(ws + O_WCA);
  unsigned short* wt_caproj = (unsigned short*)(ws + O_WCAPROJ);
  unsigned short* wt_fc     = (unsigned short*)(ws + O_WFC);
  unsigned short* wt_mproj  = (unsigned short*)(ws + O_WMPROJ);
  unsigned short* wt_down   = (unsigned short*)(ws + O_WDOWN);
  unsigned short* wt_up     = (unsigned short*)(ws + O_WUP);
  unsigned short* encbf     = (unsigned short*)(ws + O_ENC);
  unsigned short* lnout     = (unsigned short*)(ws + O_LN);
  unsigned short* hbf       = (unsigned short*)(ws + O_LN);            // after fc consumed
  unsigned short* qkvb      = (unsigned short*)(ws + O_BIG);
  unsigned short* vt_self   = (unsigned short*)(ws + O_BIG + 25165824); // alive with qkvb
  unsigned short* q2b       = (unsigned short*)(ws + O_BIG);           // after self path done
  unsigned short* kvb       = (unsigned short*)(ws + O_BIG + 8388608);
  unsigned short* vt_cross  = (unsigned short*)(ws + O_BIG + 12599296);
  unsigned short* caout     = (unsigned short*)(ws + O_BIG + 15220736);
  unsigned short* fcout     = (unsigned short*)(ws + O_BIG);           // after cross path done
  float*          xres      = (float*)(ws + O_XRES);
  float*          hf        = (float*)(ws + O_HF);
  unsigned short* attnout   = (unsigned short*)(ws + O_ATTN);
  unsigned short* dmid      = (unsigned short*)(ws + O_ATTN);          // after aproj consumed

  dim3 blk(256);
  dim3 blk5(512);

  // 1. weight transposes (f32 [K][N] -> bf16 [N][K])
  k_transpose_cvt<<<dim3(48, 16), blk, 0, stream>>>(attn_w,  wt_attn,   1024, 3072);
  k_transpose_cvt<<<dim3(16, 16), blk, 0, stream>>>(aproj_w, wt_aproj,  1024, 1024);
  k_transpose_cvt<<<dim3(48, 16), blk, 0, stream>>>(ca_w,    wt_ca,     1024, 3072);
  k_transpose_cvt<<<dim3(16, 16), blk, 0, stream>>>(caproj_w,wt_caproj, 1024, 1024);
  k_transpose_cvt<<<dim3(64, 16), blk, 0, stream>>>(fc_w,    wt_fc,     1024, 4096);
  k_transpose_cvt<<<dim3(16, 64), blk, 0, stream>>>(mproj_w, wt_mproj,  4096, 1024);
  k_transpose_cvt<<<dim3(4, 16),  blk, 0, stream>>>(down_w,  wt_down,   1024, 256);
  k_transpose_cvt<<<dim3(16, 4),  blk, 0, stream>>>(up_w,    wt_up,     256,  1024);
  // 2. encoder -> bf16
  k_cvt_bf16<<<dim3(4112), blk, 0, stream>>>(enc, encbf, 1028 * 1024);

  // 3. ln1(x) ; qkv (256²) ; V-transpose ; self-attn ; aproj + residual(x) -> xres
  k_ln<<<dim3(4096), blk, 0, stream>>>(x, ln1_g, ln1_b, lnout);
  k_g256<false><<<dim3(12, 16), blk5, 0, stream>>>(
      lnout, 1024, wt_attn, 1024, attn_b, qkvb, 3072, 1024);
  k_vtrans<<<dim3(16, 64), blk, 0, stream>>>(qkvb, 3072, 2048, 1024, vt_self, 1024);
  k_attn<true><<<dim3(16, 64), blk, 0, stream>>>(
      qkvb, 3072, qkvb, 3072, 1024, 1024, vt_self, 1024, attnout, 1024);
  k_g128<false, true, false, 1><<<dim3(8, 32), blk, 0, stream>>>(
      attnout, 1024, wt_aproj, 1024, aproj_b, x, nullptr, xres, nullptr, 4096, 1024, 1024);

  // 4. ln2(xres) ; q2 ; kv(enc) ; V-transpose ; cross-attn ; caproj + residual -> xres
  k_ln<<<dim3(4096), blk, 0, stream>>>(xres, ln2_g, ln2_b, lnout);
  k_g128<false, false, true, 0><<<dim3(8, 32), blk, 0, stream>>>(
      lnout, 1024, wt_ca, 1024, ca_b, nullptr, nullptr, nullptr, q2b, 4096, 1024, 1024);
  k_g128<false, false, true, 0><<<dim3(16, 9), blk, 0, stream>>>(
      encbf, 1024, wt_ca + (size_t)1024 * 1024, 1024, ca_b + 1024, nullptr, nullptr,
      nullptr, kvb, 1028, 2048, 1024);
  k_vtrans<<<dim3(5, 64), blk, 0, stream>>>(kvb, 2048, 1024, 257, vt_cross, 320);
  k_attn<false><<<dim3(16, 64), blk, 0, stream>>>(
      q2b, 1024, kvb, 2048, 0, 257, vt_cross, 320, caout, 257);
  k_g128<false, true, false, 1><<<dim3(8, 32), blk, 0, stream>>>(
      caout, 1024, wt_caproj, 1024, caproj_b, xres, nullptr, xres, nullptr, 4096, 1024, 1024);

  // 5. ln3(xres) ; fc+gelu (256²) ; mproj (128²)
  k_ln<<<dim3(4096), blk, 0, stream>>>(xres, ln3_g, ln3_b, lnout);
  k_g256<true><<<dim3(16, 16), blk5, 0, stream>>>(
      lnout, 1024, wt_fc, 1024, fc_b, fcout, 4096, 1024);
  k_g128<false, true, true, 0><<<dim3(8, 32), blk, 0, stream>>>(
      fcout, 4096, wt_mproj, 4096, mproj_b, nullptr, nullptr, hf, hbf, 4096, 1024, 4096);

  // 6. adapter: down+gelu ; up + up_b + h + xres -> out
  k_g128<true, false, true, 0><<<dim3(2, 32), blk, 0, stream>>>(
      hbf, 1024, wt_down, 1024, down_b, nullptr, nullptr, nullptr, dmid, 4096, 256, 1024);
  k_g128<false, true, false, 2><<<dim3(8, 32), blk, 0, stream>>>(
      dmid, 256, wt_up, 256, up_b, hf, xres, out, nullptr, 4096, 1024, 256);
}

// Round 6
// 498.897 us; speedup vs baseline: 1.0674x; 1.0121x over previous
//
#include <hip/hip_runtime.h>

typedef __attribute__((ext_vector_type(8))) short short8v;
typedef __attribute__((ext_vector_type(8))) unsigned short ushort8v;
typedef __attribute__((ext_vector_type(4))) float f32x4;

__device__ __forceinline__ unsigned short f2b(float f) {
  unsigned int u = __float_as_uint(f);
  unsigned int r = (u + 0x7FFFu + ((u >> 16) & 1u)) >> 16;
  return (unsigned short)r;
}
__device__ __forceinline__ float b2f(unsigned short h) {
  return __uint_as_float(((unsigned int)h) << 16);
}
__device__ __forceinline__ float gelu_f(float x) {
  float z = 0.7978845608028654f * (x + 0.044715f * x * x * x);
  float e = __expf(2.0f * z);
  float t = 1.0f - 2.0f / (e + 1.0f);
  return 0.5f * x * (1.0f + t);
}
__device__ __forceinline__ void gload16(const void* g, void* l) {
  __builtin_amdgcn_global_load_lds((const __attribute__((address_space(1))) unsigned int*)g,
                                   (__attribute__((address_space(3))) unsigned int*)l,
                                   16, 0, 0);
}

// ---------------- transpose + f32->bf16 convert: w[K][N] -> wt[N][K] ----------------
__global__ __launch_bounds__(256) void k_transpose_cvt(const float* __restrict__ w,
                                                       unsigned short* __restrict__ wt,
                                                       int K, int N) {
  __shared__ float tile[64][65];
  int tn = blockIdx.x * 64, tk = blockIdx.y * 64;
  int c = threadIdx.x & 63, r0 = threadIdx.x >> 6;
#pragma unroll
  for (int p = 0; p < 16; ++p) {
    int r = r0 + p * 4;
    tile[r][c] = w[(size_t)(tk + r) * N + tn + c];
  }
  __syncthreads();
#pragma unroll
  for (int p = 0; p < 16; ++p) {
    int r = r0 + p * 4;
    wt[(size_t)(tn + r) * K + tk + c] = f2b(tile[c][r]);
  }
}

__global__ void k_cvt_bf16(const float* __restrict__ in, unsigned short* __restrict__ out, int n) {
  int i = blockIdx.x * 256 + threadIdx.x;
  if (i < n) out[i] = f2b(in[i]);
}

// ---------------- LayerNorm over C=1024, out bf16 ----------------
__global__ __launch_bounds__(256) void k_ln(const float* __restrict__ in,
                                            const float* __restrict__ g,
                                            const float* __restrict__ b,
                                            unsigned short* __restrict__ out) {
  int row = blockIdx.x;
  const float* x = in + (size_t)row * 1024;
  int t = threadIdx.x;
  float v0 = x[t], v1 = x[t + 256], v2 = x[t + 512], v3 = x[t + 768];
  float s = v0 + v1 + v2 + v3;
  float s2 = v0 * v0 + v1 * v1 + v2 * v2 + v3 * v3;
#pragma unroll
  for (int m = 1; m < 64; m <<= 1) { s += __shfl_xor(s, m); s2 += __shfl_xor(s2, m); }
  __shared__ float rs[4], rs2[4];
  int w = t >> 6;
  if ((t & 63) == 0) { rs[w] = s; rs2[w] = s2; }
  __syncthreads();
  s = rs[0] + rs[1] + rs[2] + rs[3];
  s2 = rs2[0] + rs2[1] + rs2[2] + rs2[3];
  float mean = s * (1.0f / 1024.0f);
  float var = s2 * (1.0f / 1024.0f) - mean * mean;
  float rinv = rsqrtf(var + 1e-5f);
  unsigned short* o = out + (size_t)row * 1024;
  o[t]       = f2b((v0 - mean) * rinv * g[t]       + b[t]);
  o[t + 256] = f2b((v1 - mean) * rinv * g[t + 256] + b[t + 256]);
  o[t + 512] = f2b((v2 - mean) * rinv * g[t + 512] + b[t + 512]);
  o[t + 768] = f2b((v3 - mean) * rinv * g[t + 768] + b[t + 768]);
}

// ---------------- 256x256 8-phase GEMM, corrected counted-vmcnt depth ----------------
// Ring: 8 slots x 16KB (u16 slot*8192). Half h (=4T+q): slot h&7; id 0=A-ks0,1=B-ks0,
// 2=A-ks1,3=B-ks1. Phase q of tile T: ds_read (ks=q>>1, mh=q&1); STAGE(h=4T+q+6);
// odd-phase vmcnt(8) [tail: vmcnt(4)/vmcnt(0)]; barrier; lgkmcnt(0); 16 MFMA; barrier.
// Depth: 4-6 halves in flight at all times (never drains mid-loop).
// Wait proof: q=3 of T-1 issues thru 4T+5, vmcnt(8) confirms halves<=4T+1 (read phase 0
// of T, 2 barriers later). q=1 of T issues thru 4T+7, confirms <=4T+3 (read phase 2). 
template <bool GELU>
__global__ __launch_bounds__(512, 2) void k_g256p(
    const unsigned short* __restrict__ A, int lda,
    const unsigned short* __restrict__ W, int ldw,
    const float* __restrict__ bias,
    unsigned short* __restrict__ outB, int ldo, int K) {
  __shared__ unsigned short lds[65536];
  const int t = threadIdx.x;
  const int tileM = blockIdx.y * 256, tileN = blockIdx.x * 256;
  const int lane = t & 63, w = t >> 6;
  const int wm = w >> 2, wn = w & 3;
  const int lr16 = lane & 15, kc4 = lane >> 4;

  const int row1 = t >> 2, row2 = row1 + 128, cs = t & 3;
  const int c1 = (cs ^ ((row1 >> 1) & 3)) * 8;
  const int c2 = (cs ^ ((row2 >> 1) & 3)) * 8;
  const unsigned short* a1 = A + (size_t)(tileM + row1) * lda + c1;
  const unsigned short* a2 = A + (size_t)(tileM + row2) * lda + c2;
  const unsigned short* w1 = W + (size_t)(tileN + row1) * ldw + c1;
  const unsigned short* w2 = W + (size_t)(tileN + row2) * ldw + c2;

  f32x4 acc[8][4];
#pragma unroll
  for (int i = 0; i < 8; ++i)
#pragma unroll
    for (int j = 0; j < 4; ++j) acc[i][j] = f32x4{0.f, 0.f, 0.f, 0.f};

  const int nt = K >> 6;
  const int H = nt * 4;

#define STAGE_HALF(h)                                                        \
  do {                                                                       \
    int tile_s = (h) >> 2, id = (h) & 3, slot = (h) & 7;                     \
    int koff = tile_s * 64 + (id >> 1) * 32;                                 \
    unsigned short* dst = &lds[slot * 8192 + t * 8];                         \
    if (id & 1) { gload16(w1 + koff, dst); gload16(w2 + koff, dst + 4096); } \
    else        { gload16(a1 + koff, dst); gload16(a2 + koff, dst + 4096); } \
  } while (0)

#pragma unroll
  for (int h = 0; h < 6; ++h) { if (h < H) STAGE_HALF(h); }
  asm volatile("s_waitcnt vmcnt(8)" ::: "memory");   // halves 0,1 landed; 2..5 in flight
  __builtin_amdgcn_s_barrier();

  for (int T = 0; T < nt; ++T) {
    short8v bfr[4];
#pragma unroll
    for (int q = 0; q < 4; ++q) {
      const int ks = q >> 1, mh = q & 1;
      const int aslot = (((T & 1) * 4 + 2 * ks)) * 8192;
      const int bslot = (((T & 1) * 4 + 2 * ks + 1)) * 8192;
      if (mh == 0) {
#pragma unroll
        for (int n = 0; n < 4; ++n) {
          int r = wn * 64 + n * 16 + lr16;
          bfr[n] = *(const short8v*)&lds[bslot + r * 32 + (kc4 ^ ((r >> 1) & 3)) * 8];
        }
      }
      short8v aF[4];
#pragma unroll
      for (int m4 = 0; m4 < 4; ++m4) {
        int r = wm * 128 + mh * 64 + m4 * 16 + lr16;
        aF[m4] = *(const short8v*)&lds[aslot + r * 32 + (kc4 ^ ((r >> 1) & 3)) * 8];
      }
      int h = 4 * T + q + 6;
      if (h < H) STAGE_HALF(h);
      if (q & 1) {
        if (T < nt - 2)       asm volatile("s_waitcnt vmcnt(8)" ::: "memory");
        else if (T == nt - 2) {
          if (q == 1)         asm volatile("s_waitcnt vmcnt(4)" ::: "memory");
          else                asm volatile("s_waitcnt vmcnt(0)" ::: "memory");
        }
      }
      __builtin_amdgcn_s_barrier();
      asm volatile("s_waitcnt lgkmcnt(0)" ::: "memory");
      __builtin_amdgcn_sched_barrier(0);
      __builtin_amdgcn_s_setprio(1);
#pragma unroll
      for (int m4 = 0; m4 < 4; ++m4)
#pragma unroll
        for (int n = 0; n < 4; ++n)
          acc[mh * 4 + m4][n] =
              __builtin_amdgcn_mfma_f32_16x16x32_bf16(aF[m4], bfr[n], acc[mh * 4 + m4][n], 0, 0, 0);
      __builtin_amdgcn_s_setprio(0);
      __builtin_amdgcn_sched_barrier(0);
      __builtin_amdgcn_s_barrier();
    }
  }
#undef STAGE_HALF

#pragma unroll
  for (int mi = 0; mi < 8; ++mi) {
#pragma unroll
    for (int n = 0; n < 4; ++n) {
      int col = tileN + wn * 64 + n * 16 + lr16;
      float bv = bias[col];
#pragma unroll
      for (int qi = 0; qi < 4; ++qi) {
        int row = tileM + wm * 128 + mi * 16 + kc4 * 4 + qi;
        float v = acc[mi][n][qi] + bv;
        if (GELU) v = gelu_f(v);
        outB[(size_t)row * ldo + col] = f2b(v);
      }
    }
  }
}

// ---------------- 128x128 single-barrier 2-phase GEMM (M-guarded, epilogue fusions) ----
template <bool GELU, bool WF32, bool WBF16, int NRES, bool RES1B>
__global__ __launch_bounds__(256) void k_g128(
    const unsigned short* __restrict__ A, int lda,
    const unsigned short* __restrict__ W, int ldw,
    const float* __restrict__ bias,
    const float* __restrict__ res1, const unsigned short* __restrict__ res1b,
    const float* __restrict__ res2,
    float* __restrict__ outF, unsigned short* __restrict__ outB,
    int M, int N, int K) {
  __shared__ unsigned short lds[32768];
  const int t = threadIdx.x;
  const int tileM = blockIdx.y * 128, tileN = blockIdx.x * 128;
  const int lane = t & 63, w = t >> 6;
  const int wm = (w >> 1) * 64, wn = (w & 1) * 64;
  const int lr16 = lane & 15, kc4 = lane >> 4;

  const int row1 = t >> 2, row2 = row1 + 64, cs = t & 3;
  const int c1 = (cs ^ ((row1 >> 1) & 3)) * 8;
  const int c2 = (cs ^ ((row2 >> 1) & 3)) * 8;
  int gr1 = tileM + row1; if (gr1 >= M) gr1 = M - 1;
  int gr2 = tileM + row2; if (gr2 >= M) gr2 = M - 1;
  const unsigned short* a1 = A + (size_t)gr1 * lda + c1;
  const unsigned short* a2 = A + (size_t)gr2 * lda + c2;
  const unsigned short* w1 = W + (size_t)(tileN + row1) * ldw + c1;
  const unsigned short* w2 = W + (size_t)(tileN + row2) * ldw + c2;

  f32x4 acc[4][4];
#pragma unroll
  for (int i = 0; i < 4; ++i)
#pragma unroll
    for (int j = 0; j < 4; ++j) acc[i][j] = f32x4{0.f, 0.f, 0.f, 0.f};

  const int nt = K >> 6;

#define STAGE128(b, koff)                                  \
  do {                                                     \
    unsigned short* dst = &lds[(b) * 16384 + t * 8];       \
    gload16(a1 + (koff), dst);                             \
    gload16(a2 + (koff), dst + 2048);                      \
    gload16(a1 + (koff) + 32, dst + 4096);                 \
    gload16(a2 + (koff) + 32, dst + 6144);                 \
    gload16(w1 + (koff), dst + 8192);                      \
    gload16(w2 + (koff), dst + 10240);                     \
    gload16(w1 + (koff) + 32, dst + 12288);                \
    gload16(w2 + (koff) + 32, dst + 14336);                \
  } while (0)

  STAGE128(0, 0);
  asm volatile("s_waitcnt vmcnt(0)" ::: "memory");
  __builtin_amdgcn_s_barrier();

  for (int T = 0; T < nt; ++T) {
    if (T + 1 < nt) STAGE128((T + 1) & 1, (T + 1) * 64);
    const unsigned short* buf = &lds[(T & 1) * 16384];
#pragma unroll
    for (int s = 0; s < 2; ++s) {
      const unsigned short* ab = buf + s * 4096;
      const unsigned short* bb = buf + 8192 + s * 4096;
      short8v bfr[4];
#pragma unroll
      for (int n = 0; n < 4; ++n) {
        int r = wn + n * 16 + lr16;
        bfr[n] = *(const short8v*)&bb[r * 32 + (kc4 ^ ((r >> 1) & 3)) * 8];
      }
#pragma unroll
      for (int mi = 0; mi < 4; ++mi) {
        int r = wm + mi * 16 + lr16;
        short8v af = *(const short8v*)&ab[r * 32 + (kc4 ^ ((r >> 1) & 3)) * 8];
#pragma unroll
        for (int n = 0; n < 4; ++n)
          acc[mi][n] = __builtin_amdgcn_mfma_f32_16x16x32_bf16(af, bfr[n], acc[mi][n], 0, 0, 0);
      }
    }
    if (T + 1 < nt) {
      asm volatile("s_waitcnt vmcnt(0)" ::: "memory");
      __builtin_amdgcn_s_barrier();
    }
  }
#undef STAGE128

#pragma unroll
  for (int mi = 0; mi < 4; ++mi) {
#pragma unroll
    for (int n = 0; n < 4; ++n) {
      int col = tileN + wn + n * 16 + lr16;
      float bv = bias[col];
#pragma unroll
      for (int qi = 0; qi < 4; ++qi) {
        int row = tileM + wm + mi * 16 + kc4 * 4 + qi;
        if (row < M) {
          float v = acc[mi][n][qi] + bv;
          if (GELU) v = gelu_f(v);
          size_t o = (size_t)row * N + col;
          if (NRES >= 1) v += RES1B ? b2f(res1b[o]) : res1[o];
          if (NRES >= 2) v += res2[o];
          if (WF32) outF[o] = v;
          if (WBF16) outB[o] = f2b(v);
        }
      }
    }
  }
}

// ---------------- V transpose: src[b*TB+tok][src_off+h*64+d] -> dst[bh][d][tok] ----------------
__global__ __launch_bounds__(256) void k_vtrans(const unsigned short* __restrict__ src,
                                                int src_stride, int src_off, int TB,
                                                unsigned short* __restrict__ dst, int dst_tstride) {
  __shared__ unsigned short tile[64][72];
  int tb = blockIdx.x, bh = blockIdx.y;
  int b = bh >> 4, h = bh & 15;
  int t = threadIdx.x;
  int r = t >> 2, c0 = (t & 3) * 16;
  int tok = tb * 64 + r; if (tok >= TB) tok = TB - 1;
  const unsigned short* s = src + (size_t)(b * TB + tok) * src_stride + src_off + h * 64 + c0;
  *(ushort8v*)&tile[r][c0] = *(const ushort8v*)s;
  *(ushort8v*)&tile[r][c0 + 8] = *(const ushort8v*)(s + 8);
  __syncthreads();
  unsigned short tmp[16];
#pragma unroll
  for (int j = 0; j < 16; ++j) tmp[j] = tile[c0 + j][r];
  unsigned short* dp = dst + ((size_t)bh * 64 + r) * dst_tstride + tb * 64 + c0;
  *(ushort8v*)dp = *(const ushort8v*)&tmp[0];
  *(ushort8v*)(dp + 8) = *(const ushort8v*)&tmp[8];
}

// ---------------- MFMA flash attention ----------------
template <bool CAUSAL>
__global__ __launch_bounds__(256) void k_attn(
    const unsigned short* __restrict__ Qb, int q_stride,
    const unsigned short* __restrict__ Kb, int k_stride, int k_off, int TKR,
    const unsigned short* __restrict__ Vt, int vt_tstride,
    unsigned short* __restrict__ out, int Tk) {
  __shared__ unsigned short Kl[64 * 72];
  __shared__ unsigned short Vl[64 * 72];
  __shared__ unsigned short Pl[4][16 * 72];
  int qb = blockIdx.x, bh = blockIdx.y;
  int b = bh >> 4, h = bh & 15;
  int t = threadIdx.x, lane = t & 63, w = t >> 6;
  int g = lane >> 4, lc = lane & 15;

  int qrow_g = qb * 64 + w * 16 + lc;
  const unsigned short* qp = Qb + (size_t)(b * 1024 + qrow_g) * q_stride + h * 64 + g * 8;
  short8v aq0 = *(const short8v*)qp;
  short8v aq1 = *(const short8v*)(qp + 32);

  f32x4 o[4];
  float m_[4], l_[4];
#pragma unroll
  for (int dt = 0; dt < 4; ++dt) o[dt] = f32x4{0.f, 0.f, 0.f, 0.f};
#pragma unroll
  for (int r = 0; r < 4; ++r) { m_[r] = -3.0e38f; l_[r] = 0.0f; }

  int srow = t >> 2;
  int sc = (t & 3) * 16;
  int ntiles = CAUSAL ? (qb + 1) : ((Tk + 63) >> 6);

  for (int kt = 0; kt < ntiles; ++kt) {
    __syncthreads();
    {
      int kg = kt * 64 + srow;
      if (!CAUSAL && kg >= Tk) kg = Tk - 1;
      const unsigned short* ks = Kb + (size_t)(b * TKR + kg) * k_stride + k_off + h * 64 + sc;
      *(ushort8v*)&Kl[srow * 72 + sc]     = *(const ushort8v*)ks;
      *(ushort8v*)&Kl[srow * 72 + sc + 8] = *(const ushort8v*)(ks + 8);
      const unsigned short* vs = Vt + ((size_t)bh * 64 + srow) * vt_tstride + kt * 64 + sc;
      *(ushort8v*)&Vl[srow * 72 + sc]     = *(const ushort8v*)vs;
      *(ushort8v*)&Vl[srow * 72 + sc + 8] = *(const ushort8v*)(vs + 8);
    }
    __syncthreads();

    f32x4 s[4];
#pragma unroll
    for (int jt = 0; jt < 4; ++jt) {
      short8v bk0 = *(const short8v*)&Kl[(jt * 16 + lc) * 72 + g * 8];
      short8v bk1 = *(const short8v*)&Kl[(jt * 16 + lc) * 72 + g * 8 + 32];
      f32x4 acc = f32x4{0.f, 0.f, 0.f, 0.f};
      acc = __builtin_amdgcn_mfma_f32_16x16x32_bf16(aq0, bk0, acc, 0, 0, 0);
      acc = __builtin_amdgcn_mfma_f32_16x16x32_bf16(aq1, bk1, acc, 0, 0, 0);
      s[jt] = acc;
    }
#pragma unroll
    for (int jt = 0; jt < 4; ++jt)
#pragma unroll
      for (int r = 0; r < 4; ++r) {
        float sv = s[jt][r] * 0.125f;
        bool masked = CAUSAL ? (kt == qb && (jt * 16 + lc) > (w * 16 + g * 4 + r))
                             : (kt * 64 + jt * 16 + lc >= Tk);
        s[jt][r] = masked ? -3.0e38f : sv;
      }
    float f[4];
#pragma unroll
    for (int r = 0; r < 4; ++r) {
      float mx = fmaxf(fmaxf(s[0][r], s[1][r]), fmaxf(s[2][r], s[3][r]));
      mx = fmaxf(mx, __shfl_xor(mx, 1));
      mx = fmaxf(mx, __shfl_xor(mx, 2));
      mx = fmaxf(mx, __shfl_xor(mx, 4));
      mx = fmaxf(mx, __shfl_xor(mx, 8));
      float mnew = fmaxf(m_[r], mx);
      f[r] = __expf(m_[r] - mnew);
      m_[r] = mnew;
      float rsum = 0.0f;
#pragma unroll
      for (int jt = 0; jt < 4; ++jt) {
        float p = __expf(s[jt][r] - mnew);
        s[jt][r] = p;
        rsum += p;
      }
      rsum += __shfl_xor(rsum, 1);
      rsum += __shfl_xor(rsum, 2);
      rsum += __shfl_xor(rsum, 4);
      rsum += __shfl_xor(rsum, 8);
      l_[r] = l_[r] * f[r] + rsum;
    }
#pragma unroll
    for (int dt = 0; dt < 4; ++dt)
#pragma unroll
      for (int r = 0; r < 4; ++r) o[dt][r] *= f[r];
#pragma unroll
    for (int jt = 0; jt < 4; ++jt)
#pragma unroll
      for (int r = 0; r < 4; ++r)
        Pl[w][(g * 4 + r) * 72 + jt * 16 + lc] = f2b(s[jt][r]);
    short8v ap0 = *(const short8v*)&Pl[w][lc * 72 + g * 8];
    short8v ap1 = *(const short8v*)&Pl[w][lc * 72 + g * 8 + 32];
#pragma unroll
    for (int dt = 0; dt < 4; ++dt) {
      short8v bv0 = *(const short8v*)&Vl[(dt * 16 + lc) * 72 + g * 8];
      short8v bv1 = *(const short8v*)&Vl[(dt * 16 + lc) * 72 + g * 8 + 32];
      o[dt] = __builtin_amdgcn_mfma_f32_16x16x32_bf16(ap0, bv0, o[dt], 0, 0, 0);
      o[dt] = __builtin_amdgcn_mfma_f32_16x16x32_bf16(ap1, bv1, o[dt], 0, 0, 0);
    }
  }
  size_t orow = (size_t)(b * 1024 + qb * 64 + w * 16) * 1024 + h * 64;
#pragma unroll
  for (int r = 0; r < 4; ++r) {
    float inv = 1.0f / l_[r];
#pragma unroll
    for (int dt = 0; dt < 4; ++dt)
      out[orow + (size_t)(g * 4 + r) * 1024 + dt * 16 + lc] = f2b(o[dt][r] * inv);
  }
}

extern "C" void kernel_launch(void* const* d_in, const int* in_sizes, int n_in,
                              void* d_out, int out_size, void* d_ws, size_t ws_size,
                              hipStream_t stream) {
  (void)in_sizes; (void)n_in; (void)out_size; (void)ws_size;
  const float* x       = (const float*)d_in[0];
  const float* enc     = (const float*)d_in[1];
  const float* ln1_g   = (const float*)d_in[3];
  const float* ln1_b   = (const float*)d_in[4];
  const float* ln2_g   = (const float*)d_in[5];
  const float* ln2_b   = (const float*)d_in[6];
  const float* ln3_g   = (const float*)d_in[7];
  const float* ln3_b   = (const float*)d_in[8];
  const float* attn_w  = (const float*)d_in[9];
  const float* attn_b  = (const float*)d_in[10];
  const float* aproj_w = (const float*)d_in[11];
  const float* aproj_b = (const float*)d_in[12];
  const float* ca_w    = (const float*)d_in[13];
  const float* ca_b    = (const float*)d_in[14];
  const float* caproj_w= (const float*)d_in[15];
  const float* caproj_b= (const float*)d_in[16];
  const float* fc_w    = (const float*)d_in[17];
  const float* fc_b    = (const float*)d_in[18];
  const float* mproj_w = (const float*)d_in[19];
  const float* mproj_b = (const float*)d_in[20];
  const float* down_w  = (const float*)d_in[21];
  const float* down_b  = (const float*)d_in[22];
  const float* up_w    = (const float*)d_in[23];
  const float* up_b    = (const float*)d_in[24];
  float* out = (float*)d_out;
  char* ws = (char*)d_ws;

  const size_t O_WATTN = 0, O_WAPROJ = 6291456, O_WCA = 8388608, O_WCAPROJ = 14680064,
               O_WFC = 16777216, O_WMPROJ = 25165824, O_WDOWN = 33554432, O_WUP = 34078720,
               O_ENC = 34603008, O_LN = 36708352, O_BIG = 45096960,
               O_XRES = 78651392, O_ATTN = 112205824;

  unsigned short* wt_attn   = (unsigned short*)(ws + O_WATTN);
  unsigned short* wt_aproj  = (unsigned short*)(ws + O_WAPROJ);
  unsigned short* wt_ca     = (unsigned short*)(ws + O_WCA);
  unsigned short* wt_caproj = (unsigned short*)(ws + O_WCAPROJ);
  unsigned short* wt_fc     = (unsigned short*)(ws + O_WFC);
  unsigned short* wt_mproj  = (unsigned short*)(ws + O_WMPROJ);
  unsigned short* wt_down   = (unsigned short*)(ws + O_WDOWN);
  unsigned short* wt_up     = (unsigned short*)(ws + O_WUP);
  unsigned short* encbf     = (unsigned short*)(ws + O_ENC);
  unsigned short* lnout     = (unsigned short*)(ws + O_LN);
  unsigned short* hbf       = (unsigned short*)(ws + O_LN);            // after fc consumed
  unsigned short* qkvb      = (unsigned short*)(ws + O_BIG);
  unsigned short* vt_self   = (unsigned short*)(ws + O_BIG + 25165824); // alive with qkvb
  unsigned short* q2b       = (unsigned short*)(ws + O_BIG);           // after self path done
  unsigned short* kvb       = (unsigned short*)(ws + O_BIG + 8388608);
  unsigned short* vt_cross  = (unsigned short*)(ws + O_BIG + 12599296);
  unsigned short* caout     = (unsigned short*)(ws + O_BIG + 15220736);
  unsigned short* fcout     = (unsigned short*)(ws + O_BIG);           // after cross path done
  float*          xres      = (float*)(ws + O_XRES);
  unsigned short* attnout   = (unsigned short*)(ws + O_ATTN);
  unsigned short* dmid      = (unsigned short*)(ws + O_ATTN);          // after aproj consumed

  dim3 blk(256);
  dim3 blk5(512);

  // 1. weight transposes (f32 [K][N] -> bf16 [N][K])
  k_transpose_cvt<<<dim3(48, 16), blk, 0, stream>>>(attn_w,  wt_attn,   1024, 3072);
  k_transpose_cvt<<<dim3(16, 16), blk, 0, stream>>>(aproj_w, wt_aproj,  1024, 1024);
  k_transpose_cvt<<<dim3(48, 16), blk, 0, stream>>>(ca_w,    wt_ca,     1024, 3072);
  k_transpose_cvt<<<dim3(16, 16), blk, 0, stream>>>(caproj_w,wt_caproj, 1024, 1024);
  k_transpose_cvt<<<dim3(64, 16), blk, 0, stream>>>(fc_w,    wt_fc,     1024, 4096);
  k_transpose_cvt<<<dim3(16, 64), blk, 0, stream>>>(mproj_w, wt_mproj,  4096, 1024);
  k_transpose_cvt<<<dim3(4, 16),  blk, 0, stream>>>(down_w,  wt_down,   1024, 256);
  k_transpose_cvt<<<dim3(16, 4),  blk, 0, stream>>>(up_w,    wt_up,     256,  1024);
  k_cvt_bf16<<<dim3(4112), blk, 0, stream>>>(enc, encbf, 1028 * 1024);

  // 3. ln1(x) ; qkv (8-phase 256²) ; V-transpose ; self-attn ; aproj + residual(x) -> xres
  k_ln<<<dim3(4096), blk, 0, stream>>>(x, ln1_g, ln1_b, lnout);
  k_g256p<false><<<dim3(12, 16), blk5, 0, stream>>>(
      lnout, 1024, wt_attn, 1024, attn_b, qkvb, 3072, 1024);
  k_vtrans<<<dim3(16, 64), blk, 0, stream>>>(qkvb, 3072, 2048, 1024, vt_self, 1024);
  k_attn<true><<<dim3(16, 64), blk, 0, stream>>>(
      qkvb, 3072, qkvb, 3072, 1024, 1024, vt_self, 1024, attnout, 1024);
  k_g128<false, true, false, 1, false><<<dim3(8, 32), blk, 0, stream>>>(
      attnout, 1024, wt_aproj, 1024, aproj_b, x, nullptr, nullptr, xres, nullptr,
      4096, 1024, 1024);

  // 4. ln2(xres) ; q2 ; kv(enc) ; V-transpose ; cross-attn ; caproj + residual -> xres
  k_ln<<<dim3(4096), blk, 0, stream>>>(xres, ln2_g, ln2_b, lnout);
  k_g128<false, false, true, 0, false><<<dim3(8, 32), blk, 0, stream>>>(
      lnout, 1024, wt_ca, 1024, ca_b, nullptr, nullptr, nullptr, nullptr, q2b,
      4096, 1024, 1024);
  k_g128<false, false, true, 0, false><<<dim3(16, 9), blk, 0, stream>>>(
      encbf, 1024, wt_ca + (size_t)1024 * 1024, 1024, ca_b + 1024, nullptr, nullptr,
      nullptr, nullptr, kvb, 1028, 2048, 1024);
  k_vtrans<<<dim3(5, 64), blk, 0, stream>>>(kvb, 2048, 1024, 257, vt_cross, 320);
  k_attn<false><<<dim3(16, 64), blk, 0, stream>>>(
      q2b, 1024, kvb, 2048, 0, 257, vt_cross, 320, caout, 257);
  k_g128<false, true, false, 1, false><<<dim3(8, 32), blk, 0, stream>>>(
      caout, 1024, wt_caproj, 1024, caproj_b, xres, nullptr, nullptr, xres, nullptr,
      4096, 1024, 1024);

  // 5. ln3(xres) ; fc+gelu (8-phase 256²) ; mproj -> hbf (bf16 only)
  k_ln<<<dim3(4096), blk, 0, stream>>>(xres, ln3_g, ln3_b, lnout);
  k_g256p<true><<<dim3(16, 16), blk5, 0, stream>>>(
      lnout, 1024, wt_fc, 1024, fc_b, fcout, 4096, 1024);
  k_g128<false, false, true, 0, false><<<dim3(8, 32), blk, 0, stream>>>(
      fcout, 4096, wt_mproj, 4096, mproj_b, nullptr, nullptr, nullptr, nullptr, hbf,
      4096, 1024, 4096);

  // 6. adapter: down+gelu ; up + up_b + h(bf16) + xres -> out
  k_g128<true, false, true, 0, false><<<dim3(2, 32), blk, 0, stream>>>(
      hbf, 1024, wt_down, 1024, down_b, nullptr, nullptr, nullptr, nullptr, dmid,
      4096, 256, 1024);
  k_g128<false, true, false, 2, true><<<dim3(8, 32), blk, 0, stream>>>(
      dmid, 256, wt_up, 256, up_b, nullptr, hbf, xres, out, nullptr,
      4096, 1024, 256);
}